// Round 9
// baseline (590.567 us; speedup 1.0000x reference)
//
#include <hip/hip_runtime.h>
#include <hip/hip_bf16.h>

#define NPTS 262144
#define ROWS 64
#define FR 512                      // elems per fragment line (64 lanes x 8)
// LDS element map: buf0 [4][8][FR] @0, buf1 @16384, xbuf [4][2][FR] @32768 (reused for d_emb [4][1][FR])
#define BUF1_OFF 16384
#define XBUF_OFF 32768
#define LDS_BYTES ((16384*2 + 4096)*2)   // 73728 B -> 2 blocks/CU

typedef __attribute__((ext_vector_type(8))) short short8;
typedef __attribute__((ext_vector_type(4))) float f32x4;

__device__ __forceinline__ ushort bfu(float f) {
  union { float f; unsigned u; } x; x.f = f;
  unsigned r = x.u + 0x7fffu + ((x.u >> 16) & 1u);
  return (ushort)(r >> 16);
}
__device__ __forceinline__ unsigned pk2(float a, float b) {
  __hip_bfloat162 h = __float22bfloat162_rn(float2{a, b});
  return *reinterpret_cast<unsigned*>(&h);
}

// ---------------- prep: pack weights to fragment-major bf16 (R6-verified) ---
// dst layout: [(ct*nkt + kt)*64 + lane]*8 + j  ==  W[ct*16 + (lane&15)][kt*32 + (lane>>4)*8 + j]
__global__ void pack_w(const float* __restrict__ w, ushort* __restrict__ dst,
                       int OUT, int KIN, int nct, int nkt) {
  int t = blockIdx.x * 256 + threadIdx.x;
  int total = nct * nkt * 64;
  if (t >= total) return;
  int l  = t & 63;
  int kt = (t >> 6) % nkt;
  int ct = (t >> 6) / nkt;
  int row = ct * 16 + (l & 15);
  int k0  = kt * 32 + (l >> 4) * 8;
  ushort* d = dst + (size_t)t * 8;
  #pragma unroll
  for (int j = 0; j < 8; ++j) {
    int k = k0 + j;
    float v = (row < OUT && k < KIN) ? w[(size_t)row * KIN + k] : 0.f;
    d[j] = bfu(v);
  }
}

__global__ void pack_b(const float* __restrict__ b, float* __restrict__ dst, int OUT, int OUTP) {
  int i = blockIdx.x * 256 + threadIdx.x;
  if (i < OUTP) dst[i] = (i < OUT) ? b[i] : 0.f;
}

// ---------------- generic MFMA layer (fragment-major LDS, ct x r split) -----
// Fragment line (r, kt): lane l = point (l&15) of r-tile r, k = kt*32+(l>>4)*8+j.
// Wave computes NC ct-tiles x NR r-tiles (NC*NR chains); reads only its NR
// r-tiles' lines -> block LDS read volume = (waves*NR/4) * act-tile.
// Swapped MFMA: lane holds chs ct*16+lk*4+i of point-row lr; store re-fragments
// via lane renaming Lp = lr + 16*((ct&1)*2 + lk>>1), kq = ct>>1 (R6-verified).
template<int NKT, int KSPLIT, int NC, int NR, bool RELU>
__device__ __forceinline__ void layerg(
    const ushort* __restrict__ wpk, const float* __restrict__ bias,
    const ushort* a0, int s0, const ushort* a1, int s1,
    ushort* dst, int ctBase, int rBase, int lane)
{
  const int lr = lane & 15, lk = lane >> 4;
  f32x4 acc[NR][NC];
  #pragma unroll
  for (int c = 0; c < NC; ++c) {
    f32x4 b4 = *(const f32x4*)(bias + (ctBase + c) * 16 + lk * 4);
    #pragma unroll
    for (int r = 0; r < NR; ++r) acc[r][c] = b4;
  }
  #pragma unroll
  for (int kt = 0; kt < NKT; ++kt) {
    short8 av[NR];
    #pragma unroll
    for (int r = 0; r < NR; ++r) {
      const int rt = rBase + r;
      av[r] = (kt < KSPLIT)
        ? *(const short8*)(a0 + (size_t)(rt * s0 + kt) * FR + lane * 8)
        : *(const short8*)(a1 + (size_t)(rt * s1 + (kt - KSPLIT)) * FR + lane * 8);
    }
    #pragma unroll
    for (int c = 0; c < NC; ++c) {
      short8 bv = *(const short8*)(wpk + (size_t)(((ctBase + c) * NKT + kt) * 64 + lane) * 8);
      #pragma unroll
      for (int r = 0; r < NR; ++r)
        acc[r][c] = __builtin_amdgcn_mfma_f32_16x16x32_bf16(bv, av[r], acc[r][c], 0, 0, 0);
    }
  }
  #pragma unroll
  for (int c = 0; c < NC; ++c) {
    const int ct = ctBase + c;
    const int Lp = lr + 16 * ((ct & 1) * 2 + (lk >> 1));
    const int kq = ct >> 1;
    #pragma unroll
    for (int r = 0; r < NR; ++r) {
      const int rt = rBase + r;
      float v0 = acc[r][c][0], v1 = acc[r][c][1], v2 = acc[r][c][2], v3 = acc[r][c][3];
      if (RELU) {
        v0 = fmaxf(v0, 0.f); v1 = fmaxf(v1, 0.f);
        v2 = fmaxf(v2, 0.f); v3 = fmaxf(v3, 0.f);
      }
      uint2 p; p.x = pk2(v0, v1); p.y = pk2(v2, v3);
      *(uint2*)(dst + (size_t)(rt * 8 + kq) * FR + Lp * 8 + (lk & 1) * 4) = p;
    }
  }
}

// ---------------- fused NeRF ----------------
extern __shared__ ushort smem[];

__global__ __launch_bounds__(512, 4) void nerf_fused(
    const float* __restrict__ xyz, const float* __restrict__ dvec,
    const ushort* __restrict__ wp, const float* __restrict__ bp,
    float* __restrict__ out)
{
  ushort* buf0 = smem;
  ushort* buf1 = smem + BUF1_OFF;
  ushort* xbuf = smem + XBUF_OFF;
  const int tid  = threadIdx.x;
  const int row0 = blockIdx.x * ROWS;
  const int wave = tid >> 6, lane = tid & 63;
  const int lr = lane & 15, lk = lane >> 4;
  const int cg = wave & 3, rg = wave >> 2;

  // posenc(xyz) -> x_emb fragments [r][kt2][lane][8]; wave w does (r=w&3, kt=w>>2)
  {
    const int r = wave & 3, kt = wave >> 2;
    const float* x = xyz + (size_t)(row0 + r * 16 + lr) * 3;
    float xv[3] = {x[0], x[1], x[2]};
    const int c0 = kt * 32 + lk * 8;
    unsigned u[4];
    #pragma unroll
    for (int q = 0; q < 4; ++q) {
      ushort h2[2];
      #pragma unroll
      for (int hh = 0; hh < 2; ++hh) {
        int c = c0 + q * 2 + hh;
        float v;
        if (c < 3) v = xv[c];
        else if (c < 63) {
          int idx = c - 3, l = idx / 6, t = idx - l * 6;
          float f = (float)(1 << l);
          float xx = xv[t < 3 ? t : t - 3];
          v = (t < 3) ? __sinf(xx * f) : __cosf(xx * f);
        } else v = 0.f;
        h2[hh] = bfu(v);
      }
      u[q] = (unsigned)h2[0] | ((unsigned)h2[1] << 16);
    }
    *(uint4*)(xbuf + (size_t)(r * 2 + kt) * FR + lane * 8) = make_uint4(u[0], u[1], u[2], u[3]);
  }
  __syncthreads();
  layerg<2, 0, 4, 2, true >(wp + 0,      bp + 0,    xbuf, 2, xbuf, 2, buf0, cg * 4, rg * 2, lane);
  __syncthreads();
  layerg<8, 8, 4, 2, true >(wp + 16384,  bp + 256,  buf0, 8, buf0, 8, buf1, cg * 4, rg * 2, lane);
  __syncthreads();
  layerg<8, 8, 4, 2, true >(wp + 81920,  bp + 512,  buf1, 8, buf1, 8, buf0, cg * 4, rg * 2, lane);
  __syncthreads();
  layerg<8, 8, 4, 2, true >(wp + 147456, bp + 768,  buf0, 8, buf0, 8, buf1, cg * 4, rg * 2, lane);
  __syncthreads();
  layerg<8, 8, 4, 2, true >(wp + 212992, bp + 1024, buf1, 8, buf1, 8, buf0, cg * 4, rg * 2, lane);
  __syncthreads();
  // L2_0: K = 256 (buf0) + 64 (x_emb in xbuf)
  layerg<10, 8, 4, 2, true>(wp + 278528, bp + 1280, buf0, 8, xbuf, 2, buf1, cg * 4, rg * 2, lane);
  __syncthreads();
  // d_emb -> xbuf [r][1][FR] (x_emb dead; read only by LR0 much later); waves 0..3
  if (wave < 4) {
    const int r = wave;
    const float* d = dvec + (size_t)(row0 + r * 16 + lr) * 3;
    float dv[3] = {d[0], d[1], d[2]};
    const int c0 = lk * 8;
    unsigned u[4];
    #pragma unroll
    for (int q = 0; q < 4; ++q) {
      ushort h2[2];
      #pragma unroll
      for (int hh = 0; hh < 2; ++hh) {
        int c = c0 + q * 2 + hh;
        float v;
        if (c < 3) v = dv[c];
        else if (c < 27) {
          int idx = c - 3, l = idx / 6, t = idx - l * 6;
          float f = (float)(1 << l);
          float xx = dv[t < 3 ? t : t - 3];
          v = (t < 3) ? __sinf(xx * f) : __cosf(xx * f);
        } else v = 0.f;
        h2[hh] = bfu(v);
      }
      u[q] = (unsigned)h2[0] | ((unsigned)h2[1] << 16);
    }
    *(uint4*)(xbuf + (size_t)r * FR + lane * 8) = make_uint4(u[0], u[1], u[2], u[3]);
  }
  layerg<8, 8, 4, 2, true >(wp + 360448, bp + 1536, buf1, 8, buf1, 8, buf0, cg * 4, rg * 2, lane);
  __syncthreads();
  layerg<8, 8, 4, 2, true >(wp + 425984, bp + 1792, buf0, 8, buf0, 8, buf1, cg * 4, rg * 2, lane);
  __syncthreads();
  // L2_3: h (NO relu) -> buf0; sigma (ct 16, ch 256) on wave 0 from buf1
  layerg<8, 8, 4, 2, false>(wp + 491520, bp + 2048, buf1, 8, buf1, 8, buf0, cg * 4, rg * 2, lane);
  if (wave == 0) {
    const ushort* w23 = wp + 491520;
    float bb = bp[2048 + 256 + lr];
    f32x4 acc2[4];
    #pragma unroll
    for (int r = 0; r < 4; ++r) acc2[r] = (f32x4){bb, bb, bb, bb};
    #pragma unroll
    for (int kt = 0; kt < 8; ++kt) {
      short8 bv = *(const short8*)(w23 + (size_t)((16 * 8 + kt) * 64 + lane) * 8);
      #pragma unroll
      for (int r = 0; r < 4; ++r) {
        short8 av = *(const short8*)(buf1 + (size_t)(r * 8 + kt) * FR + lane * 8);
        acc2[r] = __builtin_amdgcn_mfma_f32_16x16x32_bf16(av, bv, acc2[r], 0, 0, 0);
      }
    }
    if (lr == 0) {
      #pragma unroll
      for (int r = 0; r < 4; ++r)
        #pragma unroll
        for (int i = 0; i < 4; ++i)
          out[(size_t)3 * NPTS + row0 + r * 16 + lk * 4 + i] = fmaxf(acc2[r][i], 0.f);
    }
  }
  __syncthreads();
  // LR0: K = 256 (buf0) + 32 (d_emb); out 128 = 8 ct x 4 r; wave: 2 ct x 2 r
  layerg<9, 8, 2, 2, true>(wp + 561152, bp + 2320, buf0, 8, xbuf, 1, buf1, cg * 2, rg * 2, lane);
  __syncthreads();
  // LR1: K = 128 (buf1 kt 0..3), out 3 of 16 -> sigmoid -> out; waves 0..3
  if (wave < 4) {
    const ushort* w = wp + 598016;
    float bb = bp[2448 + lr];
    f32x4 acc = (f32x4){bb, bb, bb, bb};
    #pragma unroll
    for (int kt = 0; kt < 4; ++kt) {
      short8 av = *(const short8*)(buf1 + (size_t)(wave * 8 + kt) * FR + lane * 8);
      short8 bv = *(const short8*)(w + (size_t)(kt * 64 + lane) * 8);
      acc = __builtin_amdgcn_mfma_f32_16x16x32_bf16(av, bv, acc, 0, 0, 0);
    }
    if (lr < 3) {
      #pragma unroll
      for (int i = 0; i < 4; ++i) {
        int grow = row0 + wave * 16 + lk * 4 + i;
        out[(size_t)grow * 3 + lr] = 1.f / (1.f + __expf(-acc[i]));
      }
    }
  }
}

// ---------------- host ----------------
extern "C" void kernel_launch(void* const* d_in, const int* in_sizes, int n_in,
                              void* d_out, int out_size, void* d_ws, size_t ws_size,
                              hipStream_t stream) {
  const float* xyz  = (const float*)d_in[0];
  const float* dvec = (const float*)d_in[1];
  ushort* wp = (ushort*)d_ws;
  float*  bp = (float*)((char*)d_ws + 1200128);

  struct WSpec { int idx, OUT, KIN, nct, nkt, off; };
  const WSpec wspecs[11] = {
    { 2, 256,  63, 16,  2,      0},
    { 4, 256, 256, 16,  8,  16384},
    { 6, 256, 256, 16,  8,  81920},
    { 8, 256, 256, 16,  8, 147456},
    {10, 256, 256, 16,  8, 212992},
    {12, 256, 319, 16, 10, 278528},
    {14, 256, 256, 16,  8, 360448},
    {16, 256, 256, 16,  8, 425984},
    {18, 257, 256, 17,  8, 491520},
    {20, 128, 283,  8,  9, 561152},
    {22,   3, 128,  1,  4, 598016},
  };
  for (int i = 0; i < 11; ++i) {
    int total = wspecs[i].nct * wspecs[i].nkt * 64;
    pack_w<<<dim3((total + 255) / 256), dim3(256), 0, stream>>>(
      (const float*)d_in[wspecs[i].idx], wp + wspecs[i].off,
      wspecs[i].OUT, wspecs[i].KIN, wspecs[i].nct, wspecs[i].nkt);
  }
  struct BSpec { int idx, OUT, OUTP, off; };
  const BSpec bspecs[11] = {
    { 3, 256, 256,    0}, { 5, 256, 256,  256}, { 7, 256, 256,  512}, { 9, 256, 256,  768},
    {11, 256, 256, 1024}, {13, 256, 256, 1280}, {15, 256, 256, 1536}, {17, 256, 256, 1792},
    {19, 257, 272, 2048}, {21, 128, 128, 2320}, {23,   3,  16, 2448},
  };
  for (int i = 0; i < 11; ++i) {
    pack_b<<<dim3((bspecs[i].OUTP + 255) / 256), dim3(256), 0, stream>>>(
      (const float*)d_in[bspecs[i].idx], bp + bspecs[i].off, bspecs[i].OUT, bspecs[i].OUTP);
  }

  hipFuncSetAttribute(reinterpret_cast<const void*>(nerf_fused),
                      hipFuncAttributeMaxDynamicSharedMemorySize, LDS_BYTES);
  nerf_fused<<<dim3(NPTS / ROWS), dim3(512), LDS_BYTES, stream>>>(xyz, dvec, wp, bp, (float*)d_out);
}

// Round 10
// 471.191 us; speedup vs baseline: 1.2533x; 1.2533x over previous
//
#include <hip/hip_runtime.h>
#include <hip/hip_bf16.h>

#define NPTS 262144
#define ROWS 64
#define FR 512                      // elems per fragment line (64 lanes x 8)
// LDS: buf [4 r][8 kt][FR] @0 (32 KB, in-place ping), xbuf [4][2][FR] @16384 (8 KB)
#define XBUF_OFF 16384
#define LDS_BYTES ((16384 + 4096)*2)   // 40960 B -> 4 blocks/CU (32 waves)

typedef __attribute__((ext_vector_type(8))) short short8;
typedef __attribute__((ext_vector_type(4))) float f32x4;

__device__ __forceinline__ ushort bfu(float f) {
  union { float f; unsigned u; } x; x.f = f;
  unsigned r = x.u + 0x7fffu + ((x.u >> 16) & 1u);
  return (ushort)(r >> 16);
}
__device__ __forceinline__ unsigned pk2(float a, float b) {
  __hip_bfloat162 h = __float22bfloat162_rn(float2{a, b});
  return *reinterpret_cast<unsigned*>(&h);
}

// ---------------- prep: pack weights to fragment-major bf16 (R6-verified) ---
// dst layout: [(ct*nkt + kt)*64 + lane]*8 + j  ==  W[ct*16 + (lane&15)][kt*32 + (lane>>4)*8 + j]
__global__ void pack_w(const float* __restrict__ w, ushort* __restrict__ dst,
                       int OUT, int KIN, int nct, int nkt) {
  int t = blockIdx.x * 256 + threadIdx.x;
  int total = nct * nkt * 64;
  if (t >= total) return;
  int l  = t & 63;
  int kt = (t >> 6) % nkt;
  int ct = (t >> 6) / nkt;
  int row = ct * 16 + (l & 15);
  int k0  = kt * 32 + (l >> 4) * 8;
  ushort* d = dst + (size_t)t * 8;
  #pragma unroll
  for (int j = 0; j < 8; ++j) {
    int k = k0 + j;
    float v = (row < OUT && k < KIN) ? w[(size_t)row * KIN + k] : 0.f;
    d[j] = bfu(v);
  }
}

__global__ void pack_b(const float* __restrict__ b, float* __restrict__ dst, int OUT, int OUTP) {
  int i = blockIdx.x * 256 + threadIdx.x;
  if (i < OUTP) dst[i] = (i < OUT) ? b[i] : 0.f;
}

// ---------------- generic MFMA layer (fragment-major LDS, IN-PLACE) ---------
// R6-verified inner structure: NC ct-tiles/wave over all 4 r-tiles (4*NC
// chains). Compute phase reads input fully into accs, internal barrier, then
// the write phase re-fragments IN PLACE (dst may alias a0), trailing barrier
// at call site. SIGMA: waves 0..3 additionally compute the 17th ct tile
// (channel 256) for r=wave during the read phase, store to global after.
template<int NKT, int KSPLIT, int NC, bool RELU, bool SIGMA>
__device__ __forceinline__ void layerg(
    const ushort* __restrict__ wpk, const float* __restrict__ bias,
    const ushort* a0, int s0, const ushort* a1, int s1,
    ushort* dst, int ctBase, int lane, int wave,
    const float* bp_sig, float* sig_out)
{
  const int lr = lane & 15, lk = lane >> 4;
  f32x4 acc[4][NC];
  #pragma unroll
  for (int c = 0; c < NC; ++c) {
    f32x4 b4 = *(const f32x4*)(bias + (ctBase + c) * 16 + lk * 4);
    #pragma unroll
    for (int r = 0; r < 4; ++r) acc[r][c] = b4;
  }
  #pragma unroll
  for (int kt = 0; kt < NKT; ++kt) {
    short8 av[4];
    #pragma unroll
    for (int r = 0; r < 4; ++r) {
      av[r] = (kt < KSPLIT)
        ? *(const short8*)(a0 + (size_t)(r * s0 + kt) * FR + lane * 8)
        : *(const short8*)(a1 + (size_t)(r * s1 + (kt - KSPLIT)) * FR + lane * 8);
    }
    #pragma unroll
    for (int c = 0; c < NC; ++c) {
      short8 bv = *(const short8*)(wpk + (size_t)(((ctBase + c) * NKT + kt) * 64 + lane) * 8);
      #pragma unroll
      for (int r = 0; r < 4; ++r)
        acc[r][c] = __builtin_amdgcn_mfma_f32_16x16x32_bf16(bv, av[r], acc[r][c], 0, 0, 0);
    }
  }
  // sigma tile (ct 16) read phase, R6-verified operand order, r = wave
  f32x4 acc2;
  if (SIGMA && wave < 4) {
    float bb = bp_sig[lr];
    acc2 = (f32x4){bb, bb, bb, bb};
    #pragma unroll
    for (int kt = 0; kt < NKT; ++kt) {
      short8 bv = *(const short8*)(wpk + (size_t)((16 * NKT + kt) * 64 + lane) * 8);
      short8 av = *(const short8*)(a0 + (size_t)(wave * s0 + kt) * FR + lane * 8);
      acc2 = __builtin_amdgcn_mfma_f32_16x16x32_bf16(av, bv, acc2, 0, 0, 0);
    }
  }
  __syncthreads();   // all reads of the input done -> safe to overwrite
  #pragma unroll
  for (int c = 0; c < NC; ++c) {
    const int ct = ctBase + c;
    const int Lp = lr + 16 * ((ct & 1) * 2 + (lk >> 1));
    const int kq = ct >> 1;
    #pragma unroll
    for (int r = 0; r < 4; ++r) {
      float v0 = acc[r][c][0], v1 = acc[r][c][1], v2 = acc[r][c][2], v3 = acc[r][c][3];
      if (RELU) {
        v0 = fmaxf(v0, 0.f); v1 = fmaxf(v1, 0.f);
        v2 = fmaxf(v2, 0.f); v3 = fmaxf(v3, 0.f);
      }
      uint2 p; p.x = pk2(v0, v1); p.y = pk2(v2, v3);
      *(uint2*)(dst + (size_t)(r * 8 + kq) * FR + Lp * 8 + (lk & 1) * 4) = p;
    }
  }
  if (SIGMA && wave < 4 && lr == 0) {
    #pragma unroll
    for (int i = 0; i < 4; ++i)
      sig_out[wave * 16 + lk * 4 + i] = fmaxf(acc2[i], 0.f);
  }
}

// ---------------- fused NeRF ----------------
extern __shared__ ushort smem[];

__global__ __launch_bounds__(512, 8) void nerf_fused(
    const float* __restrict__ xyz, const float* __restrict__ dvec,
    const ushort* __restrict__ wp, const float* __restrict__ bp,
    float* __restrict__ out)
{
  ushort* buf  = smem;                 // [4][8][FR], in-place activations
  ushort* xbuf = smem + XBUF_OFF;      // [4][2][FR] x_emb, later [4][1][FR] d_emb
  const int tid  = threadIdx.x;
  const int row0 = blockIdx.x * ROWS;
  const int wave = tid >> 6, lane = tid & 63;
  const int lr = lane & 15, lk = lane >> 4;

  // posenc(xyz) -> x_emb fragments [r][kt2]; wave w does (r=w&3, kt=w>>2)
  {
    const int r = wave & 3, kt = wave >> 2;
    const float* x = xyz + (size_t)(row0 + r * 16 + lr) * 3;
    float xv[3] = {x[0], x[1], x[2]};
    const int c0 = kt * 32 + lk * 8;
    unsigned u[4];
    #pragma unroll
    for (int q = 0; q < 4; ++q) {
      ushort h2[2];
      #pragma unroll
      for (int hh = 0; hh < 2; ++hh) {
        int c = c0 + q * 2 + hh;
        float v;
        if (c < 3) v = xv[c];
        else if (c < 63) {
          int idx = c - 3, l = idx / 6, t = idx - l * 6;
          float f = (float)(1 << l);
          float xx = xv[t < 3 ? t : t - 3];
          v = (t < 3) ? __sinf(xx * f) : __cosf(xx * f);
        } else v = 0.f;
        h2[hh] = bfu(v);
      }
      u[q] = (unsigned)h2[0] | ((unsigned)h2[1] << 16);
    }
    *(uint4*)(xbuf + (size_t)(r * 2 + kt) * FR + lane * 8) = make_uint4(u[0], u[1], u[2], u[3]);
  }
  __syncthreads();
  layerg<2, 0, 2, true, false>(wp + 0,      bp + 0,    xbuf, 2, xbuf, 2, buf, wave * 2, lane, wave, nullptr, nullptr);
  __syncthreads();
  layerg<8, 8, 2, true, false>(wp + 16384,  bp + 256,  buf, 8, buf, 8, buf, wave * 2, lane, wave, nullptr, nullptr);
  __syncthreads();
  layerg<8, 8, 2, true, false>(wp + 81920,  bp + 512,  buf, 8, buf, 8, buf, wave * 2, lane, wave, nullptr, nullptr);
  __syncthreads();
  layerg<8, 8, 2, true, false>(wp + 147456, bp + 768,  buf, 8, buf, 8, buf, wave * 2, lane, wave, nullptr, nullptr);
  __syncthreads();
  layerg<8, 8, 2, true, false>(wp + 212992, bp + 1024, buf, 8, buf, 8, buf, wave * 2, lane, wave, nullptr, nullptr);
  __syncthreads();
  // L2_0: K = 256 (buf) + 64 (x_emb in xbuf); xbuf dead after this read phase
  layerg<10, 8, 2, true, false>(wp + 278528, bp + 1280, buf, 8, xbuf, 2, buf, wave * 2, lane, wave, nullptr, nullptr);
  __syncthreads();
  // d_emb -> xbuf [r][1][FR]; read only by LR0 (barriers in between)
  if (wave < 4) {
    const int r = wave;
    const float* d = dvec + (size_t)(row0 + r * 16 + lr) * 3;
    float dv[3] = {d[0], d[1], d[2]};
    const int c0 = lk * 8;
    unsigned u[4];
    #pragma unroll
    for (int q = 0; q < 4; ++q) {
      ushort h2[2];
      #pragma unroll
      for (int hh = 0; hh < 2; ++hh) {
        int c = c0 + q * 2 + hh;
        float v;
        if (c < 3) v = dv[c];
        else if (c < 27) {
          int idx = c - 3, l = idx / 6, t = idx - l * 6;
          float f = (float)(1 << l);
          float xx = dv[t < 3 ? t : t - 3];
          v = (t < 3) ? __sinf(xx * f) : __cosf(xx * f);
        } else v = 0.f;
        h2[hh] = bfu(v);
      }
      u[q] = (unsigned)h2[0] | ((unsigned)h2[1] << 16);
    }
    *(uint4*)(xbuf + (size_t)r * FR + lane * 8) = make_uint4(u[0], u[1], u[2], u[3]);
  }
  layerg<8, 8, 2, true, false>(wp + 360448, bp + 1536, buf, 8, buf, 8, buf, wave * 2, lane, wave, nullptr, nullptr);
  __syncthreads();
  layerg<8, 8, 2, true, false>(wp + 425984, bp + 1792, buf, 8, buf, 8, buf, wave * 2, lane, wave, nullptr, nullptr);
  __syncthreads();
  // L2_3: h (NO relu) in place; sigma tile on waves 0..3 during read phase
  layerg<8, 8, 2, false, true>(wp + 491520, bp + 2048, buf, 8, buf, 8, buf, wave * 2, lane, wave,
                               bp + 2048 + 256, out + (size_t)3 * NPTS + row0);
  __syncthreads();
  // LR0: K = 256 (buf) + 32 (d_emb); out 128 ch = 8 ct, 1 per wave -> lines kt0..3
  layerg<9, 8, 1, true, false>(wp + 561152, bp + 2320, buf, 8, xbuf, 1, buf, wave, lane, wave, nullptr, nullptr);
  __syncthreads();
  // LR1: K = 128 (buf kt 0..3), out 3 of 16 -> sigmoid -> out; waves 0..3
  if (wave < 4) {
    const ushort* w = wp + 598016;
    float bb = bp[2448 + lr];
    f32x4 acc = (f32x4){bb, bb, bb, bb};
    #pragma unroll
    for (int kt = 0; kt < 4; ++kt) {
      short8 av = *(const short8*)(buf + (size_t)(wave * 8 + kt) * FR + lane * 8);
      short8 bv = *(const short8*)(w + (size_t)(kt * 64 + lane) * 8);
      acc = __builtin_amdgcn_mfma_f32_16x16x32_bf16(av, bv, acc, 0, 0, 0);
    }
    if (lr < 3) {
      #pragma unroll
      for (int i = 0; i < 4; ++i) {
        int grow = row0 + wave * 16 + lk * 4 + i;
        out[(size_t)grow * 3 + lr] = 1.f / (1.f + __expf(-acc[i]));
      }
    }
  }
}

// ---------------- host ----------------
extern "C" void kernel_launch(void* const* d_in, const int* in_sizes, int n_in,
                              void* d_out, int out_size, void* d_ws, size_t ws_size,
                              hipStream_t stream) {
  const float* xyz  = (const float*)d_in[0];
  const float* dvec = (const float*)d_in[1];
  ushort* wp = (ushort*)d_ws;
  float*  bp = (float*)((char*)d_ws + 1200128);

  struct WSpec { int idx, OUT, KIN, nct, nkt, off; };
  const WSpec wspecs[11] = {
    { 2, 256,  63, 16,  2,      0},
    { 4, 256, 256, 16,  8,  16384},
    { 6, 256, 256, 16,  8,  81920},
    { 8, 256, 256, 16,  8, 147456},
    {10, 256, 256, 16,  8, 212992},
    {12, 256, 319, 16, 10, 278528},
    {14, 256, 256, 16,  8, 360448},
    {16, 256, 256, 16,  8, 425984},
    {18, 257, 256, 17,  8, 491520},
    {20, 128, 283,  8,  9, 561152},
    {22,   3, 128,  1,  4, 598016},
  };
  for (int i = 0; i < 11; ++i) {
    int total = wspecs[i].nct * wspecs[i].nkt * 64;
    pack_w<<<dim3((total + 255) / 256), dim3(256), 0, stream>>>(
      (const float*)d_in[wspecs[i].idx], wp + wspecs[i].off,
      wspecs[i].OUT, wspecs[i].KIN, wspecs[i].nct, wspecs[i].nkt);
  }
  struct BSpec { int idx, OUT, OUTP, off; };
  const BSpec bspecs[11] = {
    { 3, 256, 256,    0}, { 5, 256, 256,  256}, { 7, 256, 256,  512}, { 9, 256, 256,  768},
    {11, 256, 256, 1024}, {13, 256, 256, 1280}, {15, 256, 256, 1536}, {17, 256, 256, 1792},
    {19, 257, 272, 2048}, {21, 128, 128, 2320}, {23,   3,  16, 2448},
  };
  for (int i = 0; i < 11; ++i) {
    pack_b<<<dim3((bspecs[i].OUTP + 255) / 256), dim3(256), 0, stream>>>(
      (const float*)d_in[bspecs[i].idx], bp + bspecs[i].off, bspecs[i].OUT, bspecs[i].OUTP);
  }

  hipFuncSetAttribute(reinterpret_cast<const void*>(nerf_fused),
                      hipFuncAttributeMaxDynamicSharedMemorySize, LDS_BYTES);
  nerf_fused<<<dim3(NPTS / ROWS), dim3(512), LDS_BYTES, stream>>>(xyz, dvec, wp, bp, (float*)d_out);
}

// Round 11
// 436.984 us; speedup vs baseline: 1.3515x; 1.0783x over previous
//
#include <hip/hip_runtime.h>
#include <hip/hip_bf16.h>

#define NPTS 262144
#define ROWS 64
#define FR 512                      // elems per fragment line (64 lanes x 8)
// LDS: buf [4 r][8 kt][FR] @0 (32 KB, in-place ping), xbuf [4][2][FR] @16384 (8 KB)
#define XBUF_OFF 16384
#define LDS_BYTES ((16384 + 4096)*2)   // 40960 B -> 3 blocks/CU (wave-limited)

typedef __attribute__((ext_vector_type(8))) short short8;
typedef __attribute__((ext_vector_type(4))) float f32x4;

__device__ __forceinline__ ushort bfu(float f) {
  union { float f; unsigned u; } x; x.f = f;
  unsigned r = x.u + 0x7fffu + ((x.u >> 16) & 1u);
  return (ushort)(r >> 16);
}
__device__ __forceinline__ unsigned pk2(float a, float b) {
  __hip_bfloat162 h = __float22bfloat162_rn(float2{a, b});
  return *reinterpret_cast<unsigned*>(&h);
}

// ---------------- prep: pack weights to fragment-major bf16 (R6-verified) ---
// dst layout: [(ct*nkt + kt)*64 + lane]*8 + j  ==  W[ct*16 + (lane&15)][kt*32 + (lane>>4)*8 + j]
__global__ void pack_w(const float* __restrict__ w, ushort* __restrict__ dst,
                       int OUT, int KIN, int nct, int nkt) {
  int t = blockIdx.x * 256 + threadIdx.x;
  int total = nct * nkt * 64;
  if (t >= total) return;
  int l  = t & 63;
  int kt = (t >> 6) % nkt;
  int ct = (t >> 6) / nkt;
  int row = ct * 16 + (l & 15);
  int k0  = kt * 32 + (l >> 4) * 8;
  ushort* d = dst + (size_t)t * 8;
  #pragma unroll
  for (int j = 0; j < 8; ++j) {
    int k = k0 + j;
    float v = (row < OUT && k < KIN) ? w[(size_t)row * KIN + k] : 0.f;
    d[j] = bfu(v);
  }
}

__global__ void pack_b(const float* __restrict__ b, float* __restrict__ dst, int OUT, int OUTP) {
  int i = blockIdx.x * 256 + threadIdx.x;
  if (i < OUTP) dst[i] = (i < OUT) ? b[i] : 0.f;
}

// ---------------- generic MFMA layer (fragment-major LDS, IN-PLACE) ---------
// R6-verified inner structure: NC ct-tiles/wave over all 4 r-tiles (4*NC
// chains). Compute phase reads input fully into accs, internal barrier, then
// the write phase re-fragments IN PLACE (dst may alias a0), trailing barrier
// at call site. SIGMA: waves 0..3 additionally compute the 17th ct tile
// (channel 256) for r=wave during the read phase, store to global after.
template<int NKT, int KSPLIT, int NC, bool RELU, bool SIGMA>
__device__ __forceinline__ void layerg(
    const ushort* __restrict__ wpk, const float* __restrict__ bias,
    const ushort* a0, int s0, const ushort* a1, int s1,
    ushort* dst, int ctBase, int lane, int wave,
    const float* bp_sig, float* sig_out)
{
  const int lr = lane & 15, lk = lane >> 4;
  f32x4 acc[4][NC];
  #pragma unroll
  for (int c = 0; c < NC; ++c) {
    f32x4 b4 = *(const f32x4*)(bias + (ctBase + c) * 16 + lk * 4);
    #pragma unroll
    for (int r = 0; r < 4; ++r) acc[r][c] = b4;
  }
  #pragma unroll
  for (int kt = 0; kt < NKT; ++kt) {
    short8 av[4];
    #pragma unroll
    for (int r = 0; r < 4; ++r) {
      av[r] = (kt < KSPLIT)
        ? *(const short8*)(a0 + (size_t)(r * s0 + kt) * FR + lane * 8)
        : *(const short8*)(a1 + (size_t)(r * s1 + (kt - KSPLIT)) * FR + lane * 8);
    }
    #pragma unroll
    for (int c = 0; c < NC; ++c) {
      short8 bv = *(const short8*)(wpk + (size_t)(((ctBase + c) * NKT + kt) * 64 + lane) * 8);
      #pragma unroll
      for (int r = 0; r < 4; ++r)
        acc[r][c] = __builtin_amdgcn_mfma_f32_16x16x32_bf16(bv, av[r], acc[r][c], 0, 0, 0);
    }
  }
  // sigma tile (ct 16) read phase, R6-verified operand order, r = wave
  f32x4 acc2;
  if (SIGMA && wave < 4) {
    float bb = bp_sig[lr];
    acc2 = (f32x4){bb, bb, bb, bb};
    #pragma unroll
    for (int kt = 0; kt < NKT; ++kt) {
      short8 bv = *(const short8*)(wpk + (size_t)((16 * NKT + kt) * 64 + lane) * 8);
      short8 av = *(const short8*)(a0 + (size_t)(wave * s0 + kt) * FR + lane * 8);
      acc2 = __builtin_amdgcn_mfma_f32_16x16x32_bf16(av, bv, acc2, 0, 0, 0);
    }
  }
  __syncthreads();   // all reads of the input done -> safe to overwrite
  #pragma unroll
  for (int c = 0; c < NC; ++c) {
    const int ct = ctBase + c;
    const int Lp = lr + 16 * ((ct & 1) * 2 + (lk >> 1));
    const int kq = ct >> 1;
    #pragma unroll
    for (int r = 0; r < 4; ++r) {
      float v0 = acc[r][c][0], v1 = acc[r][c][1], v2 = acc[r][c][2], v3 = acc[r][c][3];
      if (RELU) {
        v0 = fmaxf(v0, 0.f); v1 = fmaxf(v1, 0.f);
        v2 = fmaxf(v2, 0.f); v3 = fmaxf(v3, 0.f);
      }
      uint2 p; p.x = pk2(v0, v1); p.y = pk2(v2, v3);
      *(uint2*)(dst + (size_t)(r * 8 + kq) * FR + Lp * 8 + (lk & 1) * 4) = p;
    }
  }
  if (SIGMA && wave < 4 && lr == 0) {
    #pragma unroll
    for (int i = 0; i < 4; ++i)
      sig_out[wave * 16 + lk * 4 + i] = fmaxf(acc2[i], 0.f);
  }
}

// ---------------- fused NeRF ----------------
extern __shared__ ushort smem[];

__global__ __launch_bounds__(512, 6) void nerf_fused(
    const float* __restrict__ xyz, const float* __restrict__ dvec,
    const ushort* __restrict__ wp, const float* __restrict__ bp,
    float* __restrict__ out)
{
  ushort* buf  = smem;                 // [4][8][FR], in-place activations
  ushort* xbuf = smem + XBUF_OFF;      // [4][2][FR] x_emb, later [4][1][FR] d_emb
  const int tid  = threadIdx.x;
  const int row0 = blockIdx.x * ROWS;
  const int wave = tid >> 6, lane = tid & 63;
  const int lr = lane & 15, lk = lane >> 4;

  // posenc(xyz) -> x_emb fragments [r][kt2]; wave w does (r=w&3, kt=w>>2)
  {
    const int r = wave & 3, kt = wave >> 2;
    const float* x = xyz + (size_t)(row0 + r * 16 + lr) * 3;
    float xv[3] = {x[0], x[1], x[2]};
    const int c0 = kt * 32 + lk * 8;
    unsigned u[4];
    #pragma unroll
    for (int q = 0; q < 4; ++q) {
      ushort h2[2];
      #pragma unroll
      for (int hh = 0; hh < 2; ++hh) {
        int c = c0 + q * 2 + hh;
        float v;
        if (c < 3) v = xv[c];
        else if (c < 63) {
          int idx = c - 3, l = idx / 6, t = idx - l * 6;
          float f = (float)(1 << l);
          float xx = xv[t < 3 ? t : t - 3];
          v = (t < 3) ? __sinf(xx * f) : __cosf(xx * f);
        } else v = 0.f;
        h2[hh] = bfu(v);
      }
      u[q] = (unsigned)h2[0] | ((unsigned)h2[1] << 16);
    }
    *(uint4*)(xbuf + (size_t)(r * 2 + kt) * FR + lane * 8) = make_uint4(u[0], u[1], u[2], u[3]);
  }
  __syncthreads();
  layerg<2, 0, 2, true, false>(wp + 0,      bp + 0,    xbuf, 2, xbuf, 2, buf, wave * 2, lane, wave, nullptr, nullptr);
  __syncthreads();
  layerg<8, 8, 2, true, false>(wp + 16384,  bp + 256,  buf, 8, buf, 8, buf, wave * 2, lane, wave, nullptr, nullptr);
  __syncthreads();
  layerg<8, 8, 2, true, false>(wp + 81920,  bp + 512,  buf, 8, buf, 8, buf, wave * 2, lane, wave, nullptr, nullptr);
  __syncthreads();
  layerg<8, 8, 2, true, false>(wp + 147456, bp + 768,  buf, 8, buf, 8, buf, wave * 2, lane, wave, nullptr, nullptr);
  __syncthreads();
  layerg<8, 8, 2, true, false>(wp + 212992, bp + 1024, buf, 8, buf, 8, buf, wave * 2, lane, wave, nullptr, nullptr);
  __syncthreads();
  // L2_0: K = 256 (buf) + 64 (x_emb in xbuf); xbuf dead after this read phase
  layerg<10, 8, 2, true, false>(wp + 278528, bp + 1280, buf, 8, xbuf, 2, buf, wave * 2, lane, wave, nullptr, nullptr);
  __syncthreads();
  // d_emb -> xbuf [r][1][FR]; read only by LR0 (barriers in between)
  if (wave < 4) {
    const int r = wave;
    const float* d = dvec + (size_t)(row0 + r * 16 + lr) * 3;
    float dv[3] = {d[0], d[1], d[2]};
    const int c0 = lk * 8;
    unsigned u[4];
    #pragma unroll
    for (int q = 0; q < 4; ++q) {
      ushort h2[2];
      #pragma unroll
      for (int hh = 0; hh < 2; ++hh) {
        int c = c0 + q * 2 + hh;
        float v;
        if (c < 3) v = dv[c];
        else if (c < 27) {
          int idx = c - 3, l = idx / 6, t = idx - l * 6;
          float f = (float)(1 << l);
          float xx = dv[t < 3 ? t : t - 3];
          v = (t < 3) ? __sinf(xx * f) : __cosf(xx * f);
        } else v = 0.f;
        h2[hh] = bfu(v);
      }
      u[q] = (unsigned)h2[0] | ((unsigned)h2[1] << 16);
    }
    *(uint4*)(xbuf + (size_t)r * FR + lane * 8) = make_uint4(u[0], u[1], u[2], u[3]);
  }
  layerg<8, 8, 2, true, false>(wp + 360448, bp + 1536, buf, 8, buf, 8, buf, wave * 2, lane, wave, nullptr, nullptr);
  __syncthreads();
  layerg<8, 8, 2, true, false>(wp + 425984, bp + 1792, buf, 8, buf, 8, buf, wave * 2, lane, wave, nullptr, nullptr);
  __syncthreads();
  // L2_3: h (NO relu) in place; sigma tile on waves 0..3 during read phase
  layerg<8, 8, 2, false, true>(wp + 491520, bp + 2048, buf, 8, buf, 8, buf, wave * 2, lane, wave,
                               bp + 2048 + 256, out + (size_t)3 * NPTS + row0);
  __syncthreads();
  // LR0: K = 256 (buf) + 32 (d_emb); out 128 ch = 8 ct, 1 per wave -> lines kt0..3
  layerg<9, 8, 1, true, false>(wp + 561152, bp + 2320, buf, 8, xbuf, 1, buf, wave, lane, wave, nullptr, nullptr);
  __syncthreads();
  // LR1: K = 128 (buf kt 0..3), out 3 of 16 -> sigmoid -> out; waves 0..3
  if (wave < 4) {
    const ushort* w = wp + 598016;
    float bb = bp[2448 + lr];
    f32x4 acc = (f32x4){bb, bb, bb, bb};
    #pragma unroll
    for (int kt = 0; kt < 4; ++kt) {
      short8 av = *(const short8*)(buf + (size_t)(wave * 8 + kt) * FR + lane * 8);
      short8 bv = *(const short8*)(w + (size_t)(kt * 64 + lane) * 8);
      acc = __builtin_amdgcn_mfma_f32_16x16x32_bf16(av, bv, acc, 0, 0, 0);
    }
    if (lr < 3) {
      #pragma unroll
      for (int i = 0; i < 4; ++i) {
        int grow = row0 + wave * 16 + lk * 4 + i;
        out[(size_t)grow * 3 + lr] = 1.f / (1.f + __expf(-acc[i]));
      }
    }
  }
}

// ---------------- host ----------------
extern "C" void kernel_launch(void* const* d_in, const int* in_sizes, int n_in,
                              void* d_out, int out_size, void* d_ws, size_t ws_size,
                              hipStream_t stream) {
  const float* xyz  = (const float*)d_in[0];
  const float* dvec = (const float*)d_in[1];
  ushort* wp = (ushort*)d_ws;
  float*  bp = (float*)((char*)d_ws + 1200128);

  struct WSpec { int idx, OUT, KIN, nct, nkt, off; };
  const WSpec wspecs[11] = {
    { 2, 256,  63, 16,  2,      0},
    { 4, 256, 256, 16,  8,  16384},
    { 6, 256, 256, 16,  8,  81920},
    { 8, 256, 256, 16,  8, 147456},
    {10, 256, 256, 16,  8, 212992},
    {12, 256, 319, 16, 10, 278528},
    {14, 256, 256, 16,  8, 360448},
    {16, 256, 256, 16,  8, 425984},
    {18, 257, 256, 17,  8, 491520},
    {20, 128, 283,  8,  9, 561152},
    {22,   3, 128,  1,  4, 598016},
  };
  for (int i = 0; i < 11; ++i) {
    int total = wspecs[i].nct * wspecs[i].nkt * 64;
    pack_w<<<dim3((total + 255) / 256), dim3(256), 0, stream>>>(
      (const float*)d_in[wspecs[i].idx], wp + wspecs[i].off,
      wspecs[i].OUT, wspecs[i].KIN, wspecs[i].nct, wspecs[i].nkt);
  }
  struct BSpec { int idx, OUT, OUTP, off; };
  const BSpec bspecs[11] = {
    { 3, 256, 256,    0}, { 5, 256, 256,  256}, { 7, 256, 256,  512}, { 9, 256, 256,  768},
    {11, 256, 256, 1024}, {13, 256, 256, 1280}, {15, 256, 256, 1536}, {17, 256, 256, 1792},
    {19, 257, 272, 2048}, {21, 128, 128, 2320}, {23,   3,  16, 2448},
  };
  for (int i = 0; i < 11; ++i) {
    pack_b<<<dim3((bspecs[i].OUTP + 255) / 256), dim3(256), 0, stream>>>(
      (const float*)d_in[bspecs[i].idx], bp + bspecs[i].off, bspecs[i].OUT, bspecs[i].OUTP);
  }

  hipFuncSetAttribute(reinterpret_cast<const void*>(nerf_fused),
                      hipFuncAttributeMaxDynamicSharedMemorySize, LDS_BYTES);
  nerf_fused<<<dim3(NPTS / ROWS), dim3(512), LDS_BYTES, stream>>>(xyz, dvec, wp, bp, (float*)d_out);
}

// Round 12
// 340.323 us; speedup vs baseline: 1.7353x; 1.2840x over previous
//
#include <hip/hip_runtime.h>
#include <hip/hip_bf16.h>

#define NPTS 262144
#define ROWS 64
#define FR 512                      // elems per fragment line (64 lanes x 8)
// LDS: buf [4 r][8 kt][FR] @0 (32 KB, in-place ping), xbuf [4][2][FR] @16384 (8 KB)
#define XBUF_OFF 16384
#define LDS_BYTES ((16384 + 4096)*2)   // 40960 B

typedef __attribute__((ext_vector_type(8))) short short8;
typedef __attribute__((ext_vector_type(4))) float f32x4;

__device__ __forceinline__ ushort bfu(float f) {
  union { float f; unsigned u; } x; x.f = f;
  unsigned r = x.u + 0x7fffu + ((x.u >> 16) & 1u);
  return (ushort)(r >> 16);
}
__device__ __forceinline__ unsigned pk2(float a, float b) {
  __hip_bfloat162 h = __float22bfloat162_rn(float2{a, b});
  return *reinterpret_cast<unsigned*>(&h);
}

// ---------------- prep: pack weights to fragment-major bf16 (R6-verified) ---
// dst layout: [(ct*nkt + kt)*64 + lane]*8 + j  ==  W[ct*16 + (lane&15)][kt*32 + (lane>>4)*8 + j]
__global__ void pack_w(const float* __restrict__ w, ushort* __restrict__ dst,
                       int OUT, int KIN, int nct, int nkt) {
  int t = blockIdx.x * 256 + threadIdx.x;
  int total = nct * nkt * 64;
  if (t >= total) return;
  int l  = t & 63;
  int kt = (t >> 6) % nkt;
  int ct = (t >> 6) / nkt;
  int row = ct * 16 + (l & 15);
  int k0  = kt * 32 + (l >> 4) * 8;
  ushort* d = dst + (size_t)t * 8;
  #pragma unroll
  for (int j = 0; j < 8; ++j) {
    int k = k0 + j;
    float v = (row < OUT && k < KIN) ? w[(size_t)row * KIN + k] : 0.f;
    d[j] = bfu(v);
  }
}

__global__ void pack_b(const float* __restrict__ b, float* __restrict__ dst, int OUT, int OUTP) {
  int i = blockIdx.x * 256 + threadIdx.x;
  if (i < OUTP) dst[i] = (i < OUT) ? b[i] : 0.f;
}

// ---------------- generic MFMA layer (fragment-major LDS, IN-PLACE) ---------
// R6-verified inner structure: NC ct-tiles/wave over all 4 r-tiles (4*NC
// chains). Compute phase reads input fully into accs, internal barrier, then
// the write phase re-fragments IN PLACE (dst may alias a0), trailing barrier
// at call site. SIGMA: waves 0..3 additionally compute the 17th ct tile
// (channel 256) for r=wave during the read phase, store to global after.
template<int NKT, int KSPLIT, int NC, bool RELU, bool SIGMA>
__device__ __forceinline__ void layerg(
    const ushort* __restrict__ wpk, const float* __restrict__ bias,
    const ushort* a0, int s0, const ushort* a1, int s1,
    ushort* dst, int ctBase, int lane, int wave,
    const float* bp_sig, float* sig_out)
{
  const int lr = lane & 15, lk = lane >> 4;
  f32x4 acc[4][NC];
  #pragma unroll
  for (int c = 0; c < NC; ++c) {
    f32x4 b4 = *(const f32x4*)(bias + (ctBase + c) * 16 + lk * 4);
    #pragma unroll
    for (int r = 0; r < 4; ++r) acc[r][c] = b4;
  }
  #pragma unroll
  for (int kt = 0; kt < NKT; ++kt) {
    short8 av[4];
    #pragma unroll
    for (int r = 0; r < 4; ++r) {
      av[r] = (kt < KSPLIT)
        ? *(const short8*)(a0 + (size_t)(r * s0 + kt) * FR + lane * 8)
        : *(const short8*)(a1 + (size_t)(r * s1 + (kt - KSPLIT)) * FR + lane * 8);
    }
    #pragma unroll
    for (int c = 0; c < NC; ++c) {
      short8 bv = *(const short8*)(wpk + (size_t)(((ctBase + c) * NKT + kt) * 64 + lane) * 8);
      #pragma unroll
      for (int r = 0; r < 4; ++r)
        acc[r][c] = __builtin_amdgcn_mfma_f32_16x16x32_bf16(bv, av[r], acc[r][c], 0, 0, 0);
    }
  }
  // sigma tile (ct 16) read phase, R6-verified operand order, r = wave
  f32x4 acc2;
  if (SIGMA && wave < 4) {
    float bb = bp_sig[lr];
    acc2 = (f32x4){bb, bb, bb, bb};
    #pragma unroll
    for (int kt = 0; kt < NKT; ++kt) {
      short8 bv = *(const short8*)(wpk + (size_t)((16 * NKT + kt) * 64 + lane) * 8);
      short8 av = *(const short8*)(a0 + (size_t)(wave * s0 + kt) * FR + lane * 8);
      acc2 = __builtin_amdgcn_mfma_f32_16x16x32_bf16(av, bv, acc2, 0, 0, 0);
    }
  }
  __syncthreads();   // all reads of the input done -> safe to overwrite
  #pragma unroll
  for (int c = 0; c < NC; ++c) {
    const int ct = ctBase + c;
    const int Lp = lr + 16 * ((ct & 1) * 2 + (lk >> 1));
    const int kq = ct >> 1;
    #pragma unroll
    for (int r = 0; r < 4; ++r) {
      float v0 = acc[r][c][0], v1 = acc[r][c][1], v2 = acc[r][c][2], v3 = acc[r][c][3];
      if (RELU) {
        v0 = fmaxf(v0, 0.f); v1 = fmaxf(v1, 0.f);
        v2 = fmaxf(v2, 0.f); v3 = fmaxf(v3, 0.f);
      }
      uint2 p; p.x = pk2(v0, v1); p.y = pk2(v2, v3);
      *(uint2*)(dst + (size_t)(r * 8 + kq) * FR + Lp * 8 + (lk & 1) * 4) = p;
    }
  }
  if (SIGMA && wave < 4 && lr == 0) {
    #pragma unroll
    for (int i = 0; i < 4; ++i)
      sig_out[wave * 16 + lk * 4 + i] = fmaxf(acc2[i], 0.f);
  }
}

// ---------------- fused NeRF ----------------
extern __shared__ ushort smem[];

__global__ __launch_bounds__(512, 4) void nerf_fused(
    const float* __restrict__ xyz, const float* __restrict__ dvec,
    const ushort* __restrict__ wp, const float* __restrict__ bp,
    float* __restrict__ out)
{
  ushort* buf  = smem;                 // [4][8][FR], in-place activations
  ushort* xbuf = smem + XBUF_OFF;      // [4][2][FR] x_emb, later [4][1][FR] d_emb
  const int tid  = threadIdx.x;
  const int row0 = blockIdx.x * ROWS;
  const int wave = tid >> 6, lane = tid & 63;
  const int lr = lane & 15, lk = lane >> 4;

  // posenc(xyz) -> x_emb fragments [r][kt2]; wave w does (r=w&3, kt=w>>2)
  {
    const int r = wave & 3, kt = wave >> 2;
    const float* x = xyz + (size_t)(row0 + r * 16 + lr) * 3;
    float xv[3] = {x[0], x[1], x[2]};
    const int c0 = kt * 32 + lk * 8;
    unsigned u[4];
    #pragma unroll
    for (int q = 0; q < 4; ++q) {
      ushort h2[2];
      #pragma unroll
      for (int hh = 0; hh < 2; ++hh) {
        int c = c0 + q * 2 + hh;
        float v;
        if (c < 3) v = xv[c];
        else if (c < 63) {
          int idx = c - 3, l = idx / 6, t = idx - l * 6;
          float f = (float)(1 << l);
          float xx = xv[t < 3 ? t : t - 3];
          v = (t < 3) ? __sinf(xx * f) : __cosf(xx * f);
        } else v = 0.f;
        h2[hh] = bfu(v);
      }
      u[q] = (unsigned)h2[0] | ((unsigned)h2[1] << 16);
    }
    *(uint4*)(xbuf + (size_t)(r * 2 + kt) * FR + lane * 8) = make_uint4(u[0], u[1], u[2], u[3]);
  }
  __syncthreads();
  layerg<2, 0, 2, true, false>(wp + 0,      bp + 0,    xbuf, 2, xbuf, 2, buf, wave * 2, lane, wave, nullptr, nullptr);
  __syncthreads();
  layerg<8, 8, 2, true, false>(wp + 16384,  bp + 256,  buf, 8, buf, 8, buf, wave * 2, lane, wave, nullptr, nullptr);
  __syncthreads();
  layerg<8, 8, 2, true, false>(wp + 81920,  bp + 512,  buf, 8, buf, 8, buf, wave * 2, lane, wave, nullptr, nullptr);
  __syncthreads();
  layerg<8, 8, 2, true, false>(wp + 147456, bp + 768,  buf, 8, buf, 8, buf, wave * 2, lane, wave, nullptr, nullptr);
  __syncthreads();
  layerg<8, 8, 2, true, false>(wp + 212992, bp + 1024, buf, 8, buf, 8, buf, wave * 2, lane, wave, nullptr, nullptr);
  __syncthreads();
  // L2_0: K = 256 (buf) + 64 (x_emb in xbuf); xbuf dead after this read phase
  layerg<10, 8, 2, true, false>(wp + 278528, bp + 1280, buf, 8, xbuf, 2, buf, wave * 2, lane, wave, nullptr, nullptr);
  __syncthreads();
  // d_emb -> xbuf [r][1][FR]; read only by LR0 (barriers in between)
  if (wave < 4) {
    const int r = wave;
    const float* d = dvec + (size_t)(row0 + r * 16 + lr) * 3;
    float dv[3] = {d[0], d[1], d[2]};
    const int c0 = lk * 8;
    unsigned u[4];
    #pragma unroll
    for (int q = 0; q < 4; ++q) {
      ushort h2[2];
      #pragma unroll
      for (int hh = 0; hh < 2; ++hh) {
        int c = c0 + q * 2 + hh;
        float v;
        if (c < 3) v = dv[c];
        else if (c < 27) {
          int idx = c - 3, l = idx / 6, t = idx - l * 6;
          float f = (float)(1 << l);
          float xx = dv[t < 3 ? t : t - 3];
          v = (t < 3) ? __sinf(xx * f) : __cosf(xx * f);
        } else v = 0.f;
        h2[hh] = bfu(v);
      }
      u[q] = (unsigned)h2[0] | ((unsigned)h2[1] << 16);
    }
    *(uint4*)(xbuf + (size_t)r * FR + lane * 8) = make_uint4(u[0], u[1], u[2], u[3]);
  }
  layerg<8, 8, 2, true, false>(wp + 360448, bp + 1536, buf, 8, buf, 8, buf, wave * 2, lane, wave, nullptr, nullptr);
  __syncthreads();
  layerg<8, 8, 2, true, false>(wp + 425984, bp + 1792, buf, 8, buf, 8, buf, wave * 2, lane, wave, nullptr, nullptr);
  __syncthreads();
  // L2_3: h (NO relu) in place; sigma tile on waves 0..3 during read phase
  layerg<8, 8, 2, false, true>(wp + 491520, bp + 2048, buf, 8, buf, 8, buf, wave * 2, lane, wave,
                               bp + 2048 + 256, out + (size_t)3 * NPTS + row0);
  __syncthreads();
  // LR0: K = 256 (buf) + 32 (d_emb); out 128 ch = 8 ct, 1 per wave -> lines kt0..3
  layerg<9, 8, 1, true, false>(wp + 561152, bp + 2320, buf, 8, xbuf, 1, buf, wave, lane, wave, nullptr, nullptr);
  __syncthreads();
  // LR1: K = 128 (buf kt 0..3), out 3 of 16 -> sigmoid -> out; waves 0..3
  if (wave < 4) {
    const ushort* w = wp + 598016;
    float bb = bp[2448 + lr];
    f32x4 acc = (f32x4){bb, bb, bb, bb};
    #pragma unroll
    for (int kt = 0; kt < 4; ++kt) {
      short8 av = *(const short8*)(buf + (size_t)(wave * 8 + kt) * FR + lane * 8);
      short8 bv = *(const short8*)(w + (size_t)(kt * 64 + lane) * 8);
      acc = __builtin_amdgcn_mfma_f32_16x16x32_bf16(av, bv, acc, 0, 0, 0);
    }
    if (lr < 3) {
      #pragma unroll
      for (int i = 0; i < 4; ++i) {
        int grow = row0 + wave * 16 + lk * 4 + i;
        out[(size_t)grow * 3 + lr] = 1.f / (1.f + __expf(-acc[i]));
      }
    }
  }
}

// ---------------- host ----------------
extern "C" void kernel_launch(void* const* d_in, const int* in_sizes, int n_in,
                              void* d_out, int out_size, void* d_ws, size_t ws_size,
                              hipStream_t stream) {
  const float* xyz  = (const float*)d_in[0];
  const float* dvec = (const float*)d_in[1];
  ushort* wp = (ushort*)d_ws;
  float*  bp = (float*)((char*)d_ws + 1200128);

  struct WSpec { int idx, OUT, KIN, nct, nkt, off; };
  const WSpec wspecs[11] = {
    { 2, 256,  63, 16,  2,      0},
    { 4, 256, 256, 16,  8,  16384},
    { 6, 256, 256, 16,  8,  81920},
    { 8, 256, 256, 16,  8, 147456},
    {10, 256, 256, 16,  8, 212992},
    {12, 256, 319, 16, 10, 278528},
    {14, 256, 256, 16,  8, 360448},
    {16, 256, 256, 16,  8, 425984},
    {18, 257, 256, 17,  8, 491520},
    {20, 128, 283,  8,  9, 561152},
    {22,   3, 128,  1,  4, 598016},
  };
  for (int i = 0; i < 11; ++i) {
    int total = wspecs[i].nct * wspecs[i].nkt * 64;
    pack_w<<<dim3((total + 255) / 256), dim3(256), 0, stream>>>(
      (const float*)d_in[wspecs[i].idx], wp + wspecs[i].off,
      wspecs[i].OUT, wspecs[i].KIN, wspecs[i].nct, wspecs[i].nkt);
  }
  struct BSpec { int idx, OUT, OUTP, off; };
  const BSpec bspecs[11] = {
    { 3, 256, 256,    0}, { 5, 256, 256,  256}, { 7, 256, 256,  512}, { 9, 256, 256,  768},
    {11, 256, 256, 1024}, {13, 256, 256, 1280}, {15, 256, 256, 1536}, {17, 256, 256, 1792},
    {19, 257, 272, 2048}, {21, 128, 128, 2320}, {23,   3,  16, 2448},
  };
  for (int i = 0; i < 11; ++i) {
    pack_b<<<dim3((bspecs[i].OUTP + 255) / 256), dim3(256), 0, stream>>>(
      (const float*)d_in[bspecs[i].idx], bp + bspecs[i].off, bspecs[i].OUT, bspecs[i].OUTP);
  }

  hipFuncSetAttribute(reinterpret_cast<const void*>(nerf_fused),
                      hipFuncAttributeMaxDynamicSharedMemorySize, LDS_BYTES);
  nerf_fused<<<dim3(NPTS / ROWS), dim3(512), LDS_BYTES, stream>>>(xyz, dvec, wp, bp, (float*)d_out);
}